// Round 1
// baseline (507.690 us; speedup 1.0000x reference)
//
#include <hip/hip_runtime.h>

#define CIN  16
#define COUT 16
#define SNUM 4
#define PPT  4    // points (n) per thread
#define TPB  256  // threads per block

// out[b,o,n] = sum_i W[o,i,s(b,n)] * x[b,i,n] + bias[o]
__global__ __launch_bounds__(TPB) void apr_conv1x1_kernel(
    const float* __restrict__ x,      // [B, CIN, N]
    const float* __restrict__ w,      // [COUT, CIN, SNUM]
    const float* __restrict__ bias,   // [COUT]
    const int*   __restrict__ sidx,   // [B, N]
    float*       __restrict__ out,    // [B, COUT, N]
    int N)
{
    // LDS weight tile: float4 index [i][ko][s]; element j holds W[o=ko*4+j][i][s].
    // Lane-varying part of the read address is only s*16 bytes -> <=4 distinct
    // addresses per wave on 16 distinct banks -> conflict-free broadcast.
    __shared__ float4 w4[CIN * 4 * SNUM];   // 1024 floats = 4 KiB

    const int t = threadIdx.x;
    {
        // thread t owns float4 index t:  f = t*4 + j = i*64 + ko*16 + s*4 + j
        const int s  = t & 3;
        const int ko = (t >> 2) & 3;
        const int i  = t >> 4;
        float4 v;
        v.x = w[((ko * 4 + 0) * CIN + i) * SNUM + s];
        v.y = w[((ko * 4 + 1) * CIN + i) * SNUM + s];
        v.z = w[((ko * 4 + 2) * CIN + i) * SNUM + s];
        v.w = w[((ko * 4 + 3) * CIN + i) * SNUM + s];
        w4[t] = v;
    }
    __syncthreads();

    const unsigned tid  = blockIdx.x * TPB + t;
    const unsigned tpb_ = (unsigned)(N >> 2);       // threads per batch
    const unsigned b    = tid / tpb_;               // uint32 div, once
    const unsigned n    = (tid - b * tpb_) << 2;    // first of 4 consecutive n

    const float* xb = x   + (size_t)b * CIN  * N + n;
    float*       ob = out + (size_t)b * COUT * N + n;
    const int4 sv = *(const int4*)(sidx + (size_t)b * N + n);
    const int sb0 = sv.x, sb1 = sv.y, sb2 = sv.z, sb3 = sv.w;

    float acc[PPT][COUT];
    #pragma unroll
    for (int o = 0; o < COUT; ++o) {
        const float bv = bias[o];   // uniform address -> s_load, hoisted
        acc[0][o] = bv; acc[1][o] = bv; acc[2][o] = bv; acc[3][o] = bv;
    }

#define FMA4(p, wv, xs)                         \
    acc[p][ko * 4 + 0] += (wv).x * (xs);        \
    acc[p][ko * 4 + 1] += (wv).y * (xs);        \
    acc[p][ko * 4 + 2] += (wv).z * (xs);        \
    acc[p][ko * 4 + 3] += (wv).w * (xs);

    #pragma unroll
    for (int i = 0; i < CIN; ++i) {
        const float4 xv = *(const float4*)(xb + (size_t)i * N);  // coalesced 16B/lane
        #pragma unroll
        for (int ko = 0; ko < 4; ++ko) {
            const int base = i * 16 + ko * 4;   // compile-time per unrolled iter
            const float4 w0 = w4[base + sb0];   // ds_read_b128, imm offset i*256+ko*64
            const float4 w1 = w4[base + sb1];
            const float4 w2 = w4[base + sb2];
            const float4 w3 = w4[base + sb3];
            FMA4(0, w0, xv.x)
            FMA4(1, w1, xv.y)
            FMA4(2, w2, xv.z)
            FMA4(3, w3, xv.w)
        }
    }
#undef FMA4

    #pragma unroll
    for (int o = 0; o < COUT; ++o) {
        float4 r;
        r.x = acc[0][o]; r.y = acc[1][o]; r.z = acc[2][o]; r.w = acc[3][o];
        *(float4*)(ob + (size_t)o * N) = r;     // coalesced 16B/lane
    }
}

extern "C" void kernel_launch(void* const* d_in, const int* in_sizes, int n_in,
                              void* d_out, int out_size, void* d_ws, size_t ws_size,
                              hipStream_t stream) {
    const float* x    = (const float*)d_in[0];   // [B, CIN, N]
    const float* w    = (const float*)d_in[1];   // [COUT, CIN, SNUM, 1, 1]
    const float* bias = (const float*)d_in[2];   // [COUT]
    const int*   sidx = (const int*)d_in[3];     // [B, N]
    float* out = (float*)d_out;

    const int B = 2;
    const int N = in_sizes[3] / B;               // 2097152
    const int total_points = B * N;              // 4M, divisible by PPT*TPB
    const int nthreads = total_points / PPT;
    const int nblocks  = (nthreads + TPB - 1) / TPB;

    apr_conv1x1_kernel<<<nblocks, TPB, 0, stream>>>(x, w, bias, sidx, out, N);
}